// Round 5
// baseline (726.484 us; speedup 1.0000x reference)
//
#include <hip/hip_runtime.h>
#include <cstdint>
#include <cstddef>

typedef __bf16 bf16_t;
typedef __bf16 bf16x8 __attribute__((ext_vector_type(8)));
typedef __bf16 bf16x4 __attribute__((ext_vector_type(4)));
typedef float  f32x4  __attribute__((ext_vector_type(4)));
typedef float  f32x16 __attribute__((ext_vector_type(16)));

typedef __attribute__((address_space(1))) void gvoid_t;
typedef __attribute__((address_space(3))) void lvoid_t;

__device__ __forceinline__ f32x4 mfma16(bf16x8 a, bf16x8 b, f32x4 c) {
  return __builtin_amdgcn_mfma_f32_16x16x32_bf16(a, b, c, 0, 0, 0);
}
__device__ __forceinline__ f32x16 mfma32(bf16x8 a, bf16x8 b, f32x16 c) {
  return __builtin_amdgcn_mfma_f32_32x32x16_bf16(a, b, c, 0, 0, 0);
}

__device__ __forceinline__ void async_copy16(const void* g, void* l) {
  __builtin_amdgcn_global_load_lds((gvoid_t*)g, (lvoid_t*)l, 16, 0, 0);
}

__device__ __forceinline__ float gelu_tanh(float x) {
  // jax.nn.gelu approximate=True
  float u = 0.7978845608028654f * (x + 0.044715f * x * x * x);
  float e = exp2f(2.8853900817779268f * u);   // e^{2u}
  float t = 1.f - 2.f / (e + 1.f);            // tanh(u)
  return 0.5f * x * (1.f + t);
}

// ---------- batched weight transpose: f32 [K,N] -> bf16 [N,K], 8 matrices, 1 launch ----------
struct TransBatch {
  const float* src[8];
  bf16_t* dst[8];
  int K[8], N[8], bx[8], base[8];  // base = starting linear tile id
};

__global__ void transpose_batch_kernel(TransBatch d) {
  int id = blockIdx.x;
  int mi = 0;
#pragma unroll
  for (int j = 1; j < 8; j++)
    if (id >= d.base[j]) mi = j;
  int local = id - d.base[mi];
  int bxw = d.bx[mi];
  int n0 = (local % bxw) * 32, k0 = (local / bxw) * 32;
  const float* in = d.src[mi];
  bf16_t* out = d.dst[mi];
  int K = d.K[mi], N = d.N[mi];

  __shared__ float t[32][33];
  int tx = threadIdx.x, ty = threadIdx.y;
#pragma unroll
  for (int i = 0; i < 4; i++)
    t[ty + i * 8][tx] = in[(size_t)(k0 + ty + i * 8) * N + n0 + tx];
  __syncthreads();
#pragma unroll
  for (int i = 0; i < 4; i++)
    out[(size_t)(n0 + ty + i * 8) * K + k0 + tx] = (bf16_t)t[tx][ty + i * 8];
}

// ---------- V transpose: vk bf16 [4][1024][1024] (cols 0..511) -> vt [4][512][1024] ----------
__global__ void transpose_v_kernel(const bf16_t* __restrict__ vk, bf16_t* __restrict__ vt) {
  __shared__ bf16_t t[32][33];
  int b = blockIdx.z;
  int d0 = blockIdx.x * 32, m0 = blockIdx.y * 32;
  int tx = threadIdx.x, ty = threadIdx.y;
#pragma unroll
  for (int i = 0; i < 4; i++)
    t[ty + i * 8][tx] = vk[((size_t)b * 1024 + m0 + ty + i * 8) * 1024 + d0 + tx];
  __syncthreads();
#pragma unroll
  for (int i = 0; i < 4; i++)
    vt[((size_t)b * 512 + d0 + ty + i * 8) * 1024 + m0 + tx] = t[tx][ty + i * 8];
}

// ---------- f32 -> bf16 convert, two tensors in one launch ----------
__global__ void cvt2_bf16_kernel(const float* __restrict__ a, bf16_t* __restrict__ oa, int n4a,
                                 const float* __restrict__ b, bf16_t* __restrict__ ob, int n4b) {
  int i = blockIdx.x * blockDim.x + threadIdx.x;
  const float* s;
  bf16_t* o;
  int j;
  if (i < n4a) { s = a; o = oa; j = i; }
  else { j = i - n4a; if (j >= n4b) return; s = b; o = ob; }
  float4 v = ((const float4*)s)[j];
  bf16x4 r = {(bf16_t)v.x, (bf16_t)v.y, (bf16_t)v.z, (bf16_t)v.w};
  ((bf16x4*)o)[j] = r;
}

// ---------- LayerNorm (one row per block, blockDim = D) ----------
template <int D>
__global__ void ln_kernel(const float* __restrict__ x, const float* __restrict__ g,
                          const float* __restrict__ bb, bf16_t* __restrict__ out) {
  int row = blockIdx.x, t = threadIdx.x;
  float v = x[(size_t)row * D + t];
  float s = v, s2 = v * v;
#pragma unroll
  for (int o = 32; o > 0; o >>= 1) { s += __shfl_xor(s, o); s2 += __shfl_xor(s2, o); }
  __shared__ float rs[8], rs2[8];
  constexpr int NW = D / 64;
  int w = t >> 6;
  if ((t & 63) == 0) { rs[w] = s; rs2[w] = s2; }
  __syncthreads();
  if (t < 64) {
    float a = (t < NW) ? rs[t] : 0.f;
    float a2 = (t < NW) ? rs2[t] : 0.f;
#pragma unroll
    for (int o = 4; o > 0; o >>= 1) { a += __shfl_xor(a, o); a2 += __shfl_xor(a2, o); }
    if (t == 0) { rs[0] = a; rs2[0] = a2; }
  }
  __syncthreads();
  float mu = rs[0] * (1.f / D);
  float var = rs2[0] * (1.f / D) - mu * mu;
  float rr = rsqrtf(var + 1e-5f);
  out[(size_t)row * D + t] = (bf16_t)((v - mu) * rr * g[t] + bb[t]);
}

// ---------- RMSNorm over 512 (one row per block, blockDim = 512) ----------
__global__ void rms_kernel(const float* __restrict__ x, const float* __restrict__ g,
                           bf16_t* __restrict__ out) {
  int row = blockIdx.x, t = threadIdx.x;
  float v = x[(size_t)row * 512 + t];
  float s2 = v * v;
#pragma unroll
  for (int o = 32; o > 0; o >>= 1) s2 += __shfl_xor(s2, o);
  __shared__ float rs2[8];
  int w = t >> 6;
  if ((t & 63) == 0) rs2[w] = s2;
  __syncthreads();
  if (t < 64) {
    float a = (t < 8) ? rs2[t] : 0.f;
#pragma unroll
    for (int o = 4; o > 0; o >>= 1) a += __shfl_xor(a, o);
    if (t == 0) rs2[0] = a;
  }
  __syncthreads();
  float r = rsqrtf(rs2[0] * (1.f / 512.f) + 1e-6f);
  out[(size_t)row * 512 + t] = (bf16_t)(v * r * g[t]);
}

// ---------- GEMM: A bf16 [M,K] @ Bt bf16 [N,K]^T + bias, 128x128 tile, 32x32x16 MFMA ----------
// EPI: 0 = f32 out (+bias), 1 = bf16 out (+bias), 2 = bf16 out (+bias, gelu)
// Wave: 64x64 subtile = 2x2 of 32x32 MFMA tiles. A frag: m=lane&31, k=(lane>>5)*8+j.
// C/D: col=lane&31, row=(reg&3)+8*(reg>>2)+4*(lane>>5)  [m74/m101-verified layout]
template <int EPI>
__global__ __launch_bounds__(256, 2) void gemm_bt(
    const bf16_t* __restrict__ A, const bf16_t* __restrict__ Bt,
    const float* __restrict__ bias, void* __restrict__ outp,
    int M, int N, int K) {
  __shared__ __align__(16) bf16_t As[128 * 32];
  __shared__ __align__(16) bf16_t Bs[128 * 32];
  const int tid = threadIdx.x;
  const int lane = tid & 63, wv = tid >> 6;
  const int half = lane >> 5, l32 = lane & 31;
  const int m_base = blockIdx.y * 128, n_base = blockIdx.x * 128;
  const int wm = wv & 1, wn = wv >> 1;
  f32x16 acc[2][2] = {};

  for (int k0 = 0; k0 < K; k0 += 32) {
#pragma unroll
    for (int c = 0; c < 2; c++) {
      int p = c * 256 + tid;                 // chunk id: 128 rows x 4 chunks of 8 bf16
      int row = p >> 2;
      int kc = (p & 3) ^ ((row >> 1) & 3);   // XOR swizzle (uniform mod-128B cell spread)
      async_copy16(&A[(size_t)(m_base + row) * K + k0 + kc * 8], &As[(size_t)p * 8]);
      async_copy16(&Bt[(size_t)(n_base + row) * K + k0 + kc * 8], &Bs[(size_t)p * 8]);
    }
    __syncthreads();
    bf16x8 af[2][2], bfr[2][2];
#pragma unroll
    for (int mi = 0; mi < 2; mi++)
#pragma unroll
      for (int ks = 0; ks < 2; ks++) {
        int r = wm * 64 + mi * 32 + l32;
        int g = ks * 2 + half;
        af[mi][ks] = *(const bf16x8*)&As[(size_t)(r * 4 + (g ^ ((r >> 1) & 3))) * 8];
      }
#pragma unroll
    for (int ni = 0; ni < 2; ni++)
#pragma unroll
      for (int ks = 0; ks < 2; ks++) {
        int r = wn * 64 + ni * 32 + l32;
        int g = ks * 2 + half;
        bfr[ni][ks] = *(const bf16x8*)&Bs[(size_t)(r * 4 + (g ^ ((r >> 1) & 3))) * 8];
      }
#pragma unroll
    for (int ks = 0; ks < 2; ks++)
#pragma unroll
      for (int mi = 0; mi < 2; mi++)
#pragma unroll
        for (int ni = 0; ni < 2; ni++)
          acc[mi][ni] = mfma32(af[mi][ks], bfr[ni][ks], acc[mi][ni]);
    __syncthreads();
  }

#pragma unroll
  for (int mi = 0; mi < 2; mi++)
#pragma unroll
    for (int ni = 0; ni < 2; ni++) {
      int n = n_base + wn * 64 + ni * 32 + l32;
      float bv = bias[n];
#pragma unroll
      for (int r = 0; r < 16; r++) {
        int row = (r & 3) + 8 * (r >> 2) + 4 * half;
        int m = m_base + wm * 64 + mi * 32 + row;
        float v = acc[mi][ni][r] + bv;
        if (EPI == 2) v = gelu_tanh(v);
        if (EPI == 0) ((float*)outp)[(size_t)m * N + n] = v;
        else          ((bf16_t*)outp)[(size_t)m * N + n] = (bf16_t)v;
      }
    }
}

// ---------- fused dual-score attention, m97-style block-cooperative structure ----------
// grid (nq/128, H, B), 256 threads = 4 waves. Block: 128 q-rows; wave wv: 32 q-rows
// (2 independent 16-row mt tiles). 16 key-blocks (64 keys) streamed via async
// global_load_lds into shared kc/kv/vt tiles, 2 barriers per key-block.
// No-max softmax: scores O(10), exp2 safe in f32.
__global__ __launch_bounds__(256, 2) void attn_kernel(
    const bf16_t* __restrict__ qc, const bf16_t* __restrict__ qv,
    const bf16_t* __restrict__ kcb, const bf16_t* __restrict__ vkb,
    const bf16_t* __restrict__ vt, const float* __restrict__ lamp,
    bf16_t* __restrict__ vout) {
  const int b = blockIdx.z, h = blockIdx.y;
  const int tid = threadIdx.x;
  const int lane = tid & 63, wv = tid >> 6;
  const int quad = lane >> 4, l16 = lane & 15;
  const int qrow0 = blockIdx.x * 128 + wv * 32;
  const float SCL = 0.125f * 1.4426950408889634f;  // 1/sqrt(64) * log2(e)
  const float C1 = SCL, C2 = lamp[0] * SCL;

  __shared__ __align__(16) bf16_t kcS[64 * 64];
  __shared__ __align__(16) bf16_t kvS[64 * 64];
  __shared__ __align__(16) bf16_t vtS[64 * 64];
  __shared__ __align__(16) bf16_t sP[4][32 * 64];
  bf16_t* sPw = sP[wv];

  // Q fragments: A[m=q (l16)][k=d (ks*32+quad*8+j)]
  bf16x8 qcf[2][2], qvf[2][2];
#pragma unroll
  for (int mt = 0; mt < 2; mt++)
#pragma unroll
    for (int ks = 0; ks < 2; ks++) {
      size_t o = ((size_t)b * 4096 + qrow0 + mt * 16 + l16) * 512 + h * 64 + ks * 32 + quad * 8;
      qcf[mt][ks] = *(const bf16x8*)&qc[o];
      qvf[mt][ks] = *(const bf16x8*)&qv[o];
    }

  f32x4 O[2][4] = {};
  float ls[2][4] = {};

  for (int kb = 0; kb < 16; kb++) {
    // ---- stage kc/kv/vt 64x64 tiles (8 KB each): source-side XOR swizzle ----
#pragma unroll
    for (int i = 0; i < 2; i++) {
      int p = i * 256 + tid;            // 512 chunks of 16B per tile
      int row = p >> 3;                 // key row (kc/kv) or d row (vt)
      int gc = (p & 7) ^ (row & 7);     // global chunk for this LDS slot
      async_copy16(&kcb[((size_t)b * 1024 + kb * 64 + row) * 512 + h * 64 + gc * 8],
                   &kcS[(size_t)p * 8]);
      async_copy16(&vkb[((size_t)b * 1024 + kb * 64 + row) * 1024 + 512 + h * 64 + gc * 8],
                   &kvS[(size_t)p * 8]);
      async_copy16(&vt[((size_t)((b * 8 + h) * 64) + row) * 1024 + kb * 64 + gc * 8],
                   &vtS[(size_t)p * 8]);
    }
    __syncthreads();

    // ---- QK^T + exp -> per-wave P ----
#pragma unroll
    for (int nt = 0; nt < 4; nt++) {
      int krow = nt * 16 + l16;
      int kb8 = krow & 7;
      bf16x8 kc0 = *(const bf16x8*)&kcS[(size_t)(krow * 8 + (quad ^ kb8)) * 8];
      bf16x8 kc1 = *(const bf16x8*)&kcS[(size_t)(krow * 8 + ((4 + quad) ^ kb8)) * 8];
      bf16x8 kv0 = *(const bf16x8*)&kvS[(size_t)(krow * 8 + (quad ^ kb8)) * 8];
      bf16x8 kv1 = *(const bf16x8*)&kvS[(size_t)(krow * 8 + ((4 + quad) ^ kb8)) * 8];
#pragma unroll
      for (int mt = 0; mt < 2; mt++) {
        f32x4 sc = {};
        sc = mfma16(qcf[mt][0], kc0, sc);
        sc = mfma16(qcf[mt][1], kc1, sc);
        f32x4 sv = {};
        sv = mfma16(qvf[mt][0], kv0, sv);
        sv = mfma16(qvf[mt][1], kv1, sv);
#pragma unroll
        for (int r = 0; r < 4; r++) {
          float p = exp2f(sc[r] * C1 + sv[r] * C2);
          ls[mt][r] += p;
          int prow = mt * 16 + quad * 4 + r;
          int col = nt * 16 + l16;
          sPw[prow * 64 + (((col >> 3) ^ (prow & 7)) * 8) + (col & 7)] = (bf16_t)p;
        }
      }
    }
    // RAW: this wave's P writes must land before its reads (per-wave buffer)
    asm volatile("s_waitcnt lgkmcnt(0)" ::: "memory");

    // ---- PV: O[mt] += P[mt] @ V ----
#pragma unroll
    for (int ks2 = 0; ks2 < 2; ks2++) {
      bf16x8 pa[2];
#pragma unroll
      for (int mt = 0; mt < 2; mt++) {
        int prow = mt * 16 + l16;
        pa[mt] = *(const bf16x8*)&sPw[(size_t)(prow * 8 + ((ks2 * 4 + quad) ^ (prow & 7))) * 8];
      }
#pragma unroll
      for (int ntd = 0; ntd < 4; ntd++) {
        int drow = ntd * 16 + l16;
        bf16x8 vb = *(const bf16x8*)&vtS[(size_t)(drow * 8 + ((ks2 * 4 + quad) ^ (drow & 7))) * 8];
        O[0][ntd] = mfma16(pa[0], vb, O[0][ntd]);
        O[1][ntd] = mfma16(pa[1], vb, O[1][ntd]);
      }
    }
    __syncthreads();  // protect kc/kv/vt tiles before next stage (also WAR for sPw)
  }

  // ---- epilogue: denominator + write ----
#pragma unroll
  for (int mt = 0; mt < 2; mt++) {
    float inv[4];
#pragma unroll
    for (int r = 0; r < 4; r++) {
      float v = ls[mt][r];
      v += __shfl_xor(v, 1);
      v += __shfl_xor(v, 2);
      v += __shfl_xor(v, 4);
      v += __shfl_xor(v, 8);
      inv[r] = 1.f / v;
    }
#pragma unroll
    for (int ntd = 0; ntd < 4; ntd++)
#pragma unroll
      for (int r = 0; r < 4; r++) {
        size_t o = ((size_t)b * 4096 + qrow0 + mt * 16 + quad * 4 + r) * 512 + h * 64 + ntd * 16 + l16;
        vout[o] = (bf16_t)(O[mt][ntd][r] * inv[r]);
      }
  }
}

extern "C" void kernel_launch(void* const* d_in, const int* in_sizes, int n_in,
                              void* d_out, int out_size, void* d_ws, size_t ws_size,
                              hipStream_t stream) {
  (void)in_sizes; (void)n_in; (void)out_size; (void)ws_size;
  const float* coords = (const float*)d_in[0];
  const float* values = (const float*)d_in[1];
  const float* Lv     = (const float*)d_in[2];
  const float* Lc     = (const float*)d_in[3];
  const float* lam    = (const float*)d_in[4];
  const float* lvn_g  = (const float*)d_in[5];
  const float* lvn_b  = (const float*)d_in[6];
  const float* lcn_g  = (const float*)d_in[7];
  const float* lcn_b  = (const float*)d_in[8];
  const float* ck_w = (const float*)d_in[9];  const float* ck_b = (const float*)d_in[10]; const float* ck_g = (const float*)d_in[11];
  const float* cq_w = (const float*)d_in[12]; const float* cq_b = (const float*)d_in[13]; const float* cq_g = (const float*)d_in[14];
  const float* vq_w = (const float*)d_in[15]; const float* vq_b = (const float*)d_in[16]; const float* vq_g = (const float*)d_in[17];
  const float* vk_w = (const float*)d_in[18]; const float* vk_b = (const float*)d_in[19];
  const float* op_w = (const float*)d_in[20]; const float* op_b = (const float*)d_in[21];
  const float* oln_g = (const float*)d_in[22]; const float* oln_b = (const float*)d_in[23];
  const float* m1_w = (const float*)d_in[24]; const float* m1_b = (const float*)d_in[25];
  const float* m2_w = (const float*)d_in[26]; const float* m2_b = (const float*)d_in[27];
  const float* m3_w = (const float*)d_in[28]; const float* m3_b = (const float*)d_in[29];

  char* ws = (char*)d_ws;
  size_t off = 0;
  auto alloc = [&](size_t bytes) { void* p = ws + off; off += (bytes + 255) & ~(size_t)255; return p; };

  // persistent region
  bf16_t* wt_m1 = (bf16_t*)alloc((size_t)512 * 2048 * 2);
  bf16_t* wt_m2 = (bf16_t*)alloc((size_t)2048 * 2048 * 2);
  bf16_t* wt_m3 = (bf16_t*)alloc((size_t)2048 * 512 * 2);
  float*  scr0  = (float*) alloc((size_t)16384 * 512 * 4);
  bf16_t* qv_bf = (bf16_t*)alloc((size_t)16384 * 512 * 2);
  bf16_t* qc_bf = (bf16_t*)alloc((size_t)16384 * 512 * 2);
  bf16_t* voutb = (bf16_t*)alloc((size_t)16384 * 512 * 2);
  bf16_t* h0    = (bf16_t*)alloc((size_t)16384 * 512 * 2);
  bf16_t* h1    = (bf16_t*)alloc((size_t)16384 * 2048 * 2);
  bf16_t* h2    = (bf16_t*)alloc((size_t)16384 * 2048 * 2);

  // overlay region: everything here is dead before h1 is written (m1 GEMM)
  size_t ov = (size_t)((char*)h1 - ws);
  auto oalloc = [&](size_t bytes) { void* p = ws + ov; ov += (bytes + 255) & ~(size_t)255; return p; };
  bf16_t* wt_vk = (bf16_t*)oalloc((size_t)1024 * 512 * 2);
  bf16_t* wt_ck = (bf16_t*)oalloc((size_t)512 * 128 * 2);
  bf16_t* wt_cq = (bf16_t*)oalloc((size_t)512 * 128 * 2);
  bf16_t* wt_vq = (bf16_t*)oalloc((size_t)512 * 512 * 2);
  bf16_t* wt_op = (bf16_t*)oalloc((size_t)512 * 512 * 2);
  bf16_t* lv_ln = (bf16_t*)oalloc((size_t)4096 * 512 * 2);
  bf16_t* lc_ln = (bf16_t*)oalloc((size_t)4096 * 128 * 2);
  bf16_t* vkob  = (bf16_t*)oalloc((size_t)4096 * 1024 * 2);
  float*  kc_f  = (float*) oalloc((size_t)4096 * 512 * 4);
  bf16_t* kc_bf = (bf16_t*)oalloc((size_t)4096 * 512 * 2);
  bf16_t* val_bf= (bf16_t*)oalloc((size_t)16384 * 512 * 2);
  bf16_t* crd_bf= (bf16_t*)oalloc((size_t)16384 * 128 * 2);
  bf16_t* vt    = (bf16_t*)oalloc((size_t)4 * 512 * 1024 * 2);

  // ---- single batched transpose launch for all 8 weights ----
  TransBatch tb8;
  const float* srcs[8] = {vk_w, ck_w, cq_w, vq_w, op_w, m1_w, m2_w, m3_w};
  bf16_t* dsts[8] = {wt_vk, wt_ck, wt_cq, wt_vq, wt_op, wt_m1, wt_m2, wt_m3};
  int Ks[8] = {512, 128, 128, 512, 512, 512, 2048, 2048};
  int Ns[8] = {1024, 512, 512, 512, 512, 2048, 2048, 512};
  int cum = 0;
  for (int i = 0; i < 8; i++) {
    tb8.src[i] = srcs[i]; tb8.dst[i] = dsts[i];
    tb8.K[i] = Ks[i]; tb8.N[i] = Ns[i];
    tb8.bx[i] = Ns[i] / 32;
    tb8.base[i] = cum;
    cum += (Ns[i] / 32) * (Ks[i] / 32);
  }
  transpose_batch_kernel<<<cum, dim3(32, 8), 0, stream>>>(tb8);

  cvt2_bf16_kernel<<<(16384 * 512 / 4 + 16384 * 128 / 4 + 255) / 256, 256, 0, stream>>>(
      values, val_bf, 16384 * 512 / 4, coords, crd_bf, 16384 * 128 / 4);

  ln_kernel<512><<<4096, 512, 0, stream>>>(Lv, lvn_g, lvn_b, lv_ln);
  ln_kernel<128><<<4096, 128, 0, stream>>>(Lc, lcn_g, lcn_b, lc_ln);

  gemm_bt<1><<<dim3(8, 32), 256, 0, stream>>>(lv_ln, wt_vk, vk_b, vkob, 4096, 1024, 512);
  gemm_bt<0><<<dim3(4, 32), 256, 0, stream>>>(lc_ln, wt_ck, ck_b, kc_f, 4096, 512, 128);
  rms_kernel<<<4096, 512, 0, stream>>>(kc_f, ck_g, kc_bf);

  gemm_bt<0><<<dim3(4, 128), 256, 0, stream>>>(val_bf, wt_vq, vq_b, scr0, 16384, 512, 512);
  rms_kernel<<<16384, 512, 0, stream>>>(scr0, vq_g, qv_bf);
  gemm_bt<0><<<dim3(4, 128), 256, 0, stream>>>(crd_bf, wt_cq, cq_b, scr0, 16384, 512, 128);
  rms_kernel<<<16384, 512, 0, stream>>>(scr0, cq_g, qc_bf);

  transpose_v_kernel<<<dim3(16, 32, 4), dim3(32, 8), 0, stream>>>(vkob, vt);

  attn_kernel<<<dim3(32, 8, 4), 256, 0, stream>>>(qc_bf, qv_bf, kc_bf, vkob, vt, lam, voutb);

  gemm_bt<0><<<dim3(4, 128), 256, 0, stream>>>(voutb, wt_op, op_b, scr0, 16384, 512, 512);
  ln_kernel<512><<<16384, 512, 0, stream>>>(scr0, oln_g, oln_b, h0);

  gemm_bt<2><<<dim3(16, 128), 256, 0, stream>>>(h0, wt_m1, m1_b, h1, 16384, 2048, 512);
  gemm_bt<2><<<dim3(16, 128), 256, 0, stream>>>(h1, wt_m2, m2_b, h2, 16384, 2048, 2048);
  gemm_bt<0><<<dim3(4, 128), 256, 0, stream>>>(h2, wt_m3, m3_b, (float*)d_out, 16384, 512, 2048);
}

// Round 6
// 700.672 us; speedup vs baseline: 1.0368x; 1.0368x over previous
//
#include <hip/hip_runtime.h>
#include <cstdint>
#include <cstddef>

typedef __bf16 bf16_t;
typedef __bf16 bf16x8 __attribute__((ext_vector_type(8)));
typedef __bf16 bf16x4 __attribute__((ext_vector_type(4)));
typedef float  f32x4  __attribute__((ext_vector_type(4)));

typedef __attribute__((address_space(1))) void gvoid_t;
typedef __attribute__((address_space(3))) void lvoid_t;

__device__ __forceinline__ f32x4 mfma16(bf16x8 a, bf16x8 b, f32x4 c) {
  return __builtin_amdgcn_mfma_f32_16x16x32_bf16(a, b, c, 0, 0, 0);
}

__device__ __forceinline__ void async_copy16(const void* g, void* l) {
  __builtin_amdgcn_global_load_lds((gvoid_t*)g, (lvoid_t*)l, 16, 0, 0);
}

__device__ __forceinline__ float gelu_tanh(float x) {
  // jax.nn.gelu approximate=True
  float u = 0.7978845608028654f * (x + 0.044715f * x * x * x);
  float e = exp2f(2.8853900817779268f * u);   // e^{2u}
  float t = 1.f - 2.f / (e + 1.f);            // tanh(u)
  return 0.5f * x * (1.f + t);
}

// ---------- batched weight transpose: f32 [K,N] -> bf16 [N,K], 8 matrices, 1 launch ----------
struct TransBatch {
  const float* src[8];
  bf16_t* dst[8];
  int K[8], N[8], bx[8], base[8];  // base = starting linear tile id
};

__global__ void transpose_batch_kernel(TransBatch d) {
  int id = blockIdx.x;
  int mi = 0;
#pragma unroll
  for (int j = 1; j < 8; j++)
    if (id >= d.base[j]) mi = j;
  int local = id - d.base[mi];
  int bxw = d.bx[mi];
  int n0 = (local % bxw) * 32, k0 = (local / bxw) * 32;
  const float* in = d.src[mi];
  bf16_t* out = d.dst[mi];
  int K = d.K[mi], N = d.N[mi];

  __shared__ float t[32][33];
  int tx = threadIdx.x, ty = threadIdx.y;
#pragma unroll
  for (int i = 0; i < 4; i++)
    t[ty + i * 8][tx] = in[(size_t)(k0 + ty + i * 8) * N + n0 + tx];
  __syncthreads();
#pragma unroll
  for (int i = 0; i < 4; i++)
    out[(size_t)(n0 + ty + i * 8) * K + k0 + tx] = (bf16_t)t[tx][ty + i * 8];
}

// ---------- V transpose: vk bf16 [4][1024][1024] (cols 0..511) -> vt [4][512][1024] ----------
__global__ void transpose_v_kernel(const bf16_t* __restrict__ vk, bf16_t* __restrict__ vt) {
  __shared__ bf16_t t[32][33];
  int b = blockIdx.z;
  int d0 = blockIdx.x * 32, m0 = blockIdx.y * 32;
  int tx = threadIdx.x, ty = threadIdx.y;
#pragma unroll
  for (int i = 0; i < 4; i++)
    t[ty + i * 8][tx] = vk[((size_t)b * 1024 + m0 + ty + i * 8) * 1024 + d0 + tx];
  __syncthreads();
#pragma unroll
  for (int i = 0; i < 4; i++)
    vt[((size_t)b * 512 + d0 + ty + i * 8) * 1024 + m0 + tx] = t[tx][ty + i * 8];
}

// ---------- f32 -> bf16 convert, two tensors in one launch ----------
__global__ void cvt2_bf16_kernel(const float* __restrict__ a, bf16_t* __restrict__ oa, int n4a,
                                 const float* __restrict__ b, bf16_t* __restrict__ ob, int n4b) {
  int i = blockIdx.x * blockDim.x + threadIdx.x;
  const float* s;
  bf16_t* o;
  int j;
  if (i < n4a) { s = a; o = oa; j = i; }
  else { j = i - n4a; if (j >= n4b) return; s = b; o = ob; }
  float4 v = ((const float4*)s)[j];
  bf16x4 r = {(bf16_t)v.x, (bf16_t)v.y, (bf16_t)v.z, (bf16_t)v.w};
  ((bf16x4*)o)[j] = r;
}

// ---------- LayerNorm (one row per block, blockDim = D) ----------
template <int D>
__global__ void ln_kernel(const float* __restrict__ x, const float* __restrict__ g,
                          const float* __restrict__ bb, bf16_t* __restrict__ out) {
  int row = blockIdx.x, t = threadIdx.x;
  float v = x[(size_t)row * D + t];
  float s = v, s2 = v * v;
#pragma unroll
  for (int o = 32; o > 0; o >>= 1) { s += __shfl_xor(s, o); s2 += __shfl_xor(s2, o); }
  __shared__ float rs[8], rs2[8];
  constexpr int NW = D / 64;
  int w = t >> 6;
  if ((t & 63) == 0) { rs[w] = s; rs2[w] = s2; }
  __syncthreads();
  if (t < 64) {
    float a = (t < NW) ? rs[t] : 0.f;
    float a2 = (t < NW) ? rs2[t] : 0.f;
#pragma unroll
    for (int o = 4; o > 0; o >>= 1) { a += __shfl_xor(a, o); a2 += __shfl_xor(a2, o); }
    if (t == 0) { rs[0] = a; rs2[0] = a2; }
  }
  __syncthreads();
  float mu = rs[0] * (1.f / D);
  float var = rs2[0] * (1.f / D) - mu * mu;
  float rr = rsqrtf(var + 1e-5f);
  out[(size_t)row * D + t] = (bf16_t)((v - mu) * rr * g[t] + bb[t]);
}

// ---------- RMSNorm over 512 (one row per block, blockDim = 512) ----------
__global__ void rms_kernel(const float* __restrict__ x, const float* __restrict__ g,
                           bf16_t* __restrict__ out) {
  int row = blockIdx.x, t = threadIdx.x;
  float v = x[(size_t)row * 512 + t];
  float s2 = v * v;
#pragma unroll
  for (int o = 32; o > 0; o >>= 1) s2 += __shfl_xor(s2, o);
  __shared__ float rs2[8];
  int w = t >> 6;
  if ((t & 63) == 0) rs2[w] = s2;
  __syncthreads();
  if (t < 64) {
    float a = (t < 8) ? rs2[t] : 0.f;
#pragma unroll
    for (int o = 4; o > 0; o >>= 1) a += __shfl_xor(a, o);
    if (t == 0) rs2[0] = a;
  }
  __syncthreads();
  float r = rsqrtf(rs2[0] * (1.f / 512.f) + 1e-6f);
  out[(size_t)row * 512 + t] = (bf16_t)(v * r * g[t]);
}

// ---------- GEMM 128x128 tile, 16x16x32 MFMA (R4-proven zero-conflict scheme) ----------
// EPI: 0 = f32 out (+bias), 1 = bf16 out (+bias), 2 = bf16 out (+bias, gelu)
template <int EPI>
__global__ __launch_bounds__(256, 2) void gemm_bt(
    const bf16_t* __restrict__ A, const bf16_t* __restrict__ Bt,
    const float* __restrict__ bias, void* __restrict__ outp,
    int M, int N, int K) {
  __shared__ __align__(16) bf16_t As[128 * 32];
  __shared__ __align__(16) bf16_t Bs[128 * 32];
  const int tid = threadIdx.x;
  const int lane = tid & 63, wv = tid >> 6;
  const int quad = lane >> 4, l16 = lane & 15;
  const int m_base = blockIdx.y * 128, n_base = blockIdx.x * 128;
  const int wm = wv & 1, wn = wv >> 1;
  f32x4 acc[4][4] = {};

  for (int k0 = 0; k0 < K; k0 += 32) {
#pragma unroll
    for (int c = 0; c < 2; c++) {
      int p = c * 256 + tid;                 // chunk id: 128 rows x 4 chunks of 8 bf16
      int row = p >> 2;
      int kc = (p & 3) ^ ((row >> 1) & 3);   // XOR swizzle (bank-conflict-free reads)
      async_copy16(&A[(size_t)(m_base + row) * K + k0 + kc * 8], &As[(size_t)p * 8]);
      async_copy16(&Bt[(size_t)(n_base + row) * K + k0 + kc * 8], &Bs[(size_t)p * 8]);
    }
    __syncthreads();
    bf16x8 af[4], bfr[4];
#pragma unroll
    for (int mi = 0; mi < 4; mi++) {
      int r = wm * 64 + mi * 16 + l16;
      int kc = quad ^ ((r >> 1) & 3);
      af[mi] = *(const bf16x8*)&As[(size_t)(r * 4 + kc) * 8];
    }
#pragma unroll
    for (int ni = 0; ni < 4; ni++) {
      int r = wn * 64 + ni * 16 + l16;
      int kc = quad ^ ((r >> 1) & 3);
      bfr[ni] = *(const bf16x8*)&Bs[(size_t)(r * 4 + kc) * 8];
    }
#pragma unroll
    for (int mi = 0; mi < 4; mi++)
#pragma unroll
      for (int ni = 0; ni < 4; ni++)
        acc[mi][ni] = mfma16(af[mi], bfr[ni], acc[mi][ni]);
    __syncthreads();
  }

#pragma unroll
  for (int mi = 0; mi < 4; mi++) {
    int m = m_base + wm * 64 + mi * 16 + quad * 4;
#pragma unroll
    for (int ni = 0; ni < 4; ni++) {
      int n = n_base + wn * 64 + ni * 16 + l16;
      float bv = bias[n];
#pragma unroll
      for (int r2 = 0; r2 < 4; r2++) {
        float v = acc[mi][ni][r2] + bv;
        if (EPI == 2) v = gelu_tanh(v);
        if (EPI == 0) ((float*)outp)[(size_t)(m + r2) * N + n] = v;
        else          ((bf16_t*)outp)[(size_t)(m + r2) * N + n] = (bf16_t)v;
      }
    }
  }
}

// ---------- GEMM 64x128 tile for small-N tail GEMMs (2x the blocks of 128x128) ----------
// 4 waves, each 32x64 (2 mt x 4 ni of 16x16). 12 KB LDS.
template <int EPI>
__global__ __launch_bounds__(256, 2) void gemm64(
    const bf16_t* __restrict__ A, const bf16_t* __restrict__ Bt,
    const float* __restrict__ bias, void* __restrict__ outp,
    int M, int N, int K) {
  __shared__ __align__(16) bf16_t As[64 * 32];
  __shared__ __align__(16) bf16_t Bs[128 * 32];
  const int tid = threadIdx.x;
  const int lane = tid & 63, wv = tid >> 6;
  const int quad = lane >> 4, l16 = lane & 15;
  const int m_base = blockIdx.y * 64, n_base = blockIdx.x * 128;
  const int wm = wv & 1, wn = wv >> 1;
  f32x4 acc[2][4] = {};

  for (int k0 = 0; k0 < K; k0 += 32) {
    {
      int p = tid;                           // A: 64 rows x 4 chunks = 256
      int row = p >> 2;
      int kc = (p & 3) ^ ((row >> 1) & 3);
      async_copy16(&A[(size_t)(m_base + row) * K + k0 + kc * 8], &As[(size_t)p * 8]);
    }
#pragma unroll
    for (int c = 0; c < 2; c++) {
      int p = c * 256 + tid;                 // B: 128 rows x 4 chunks = 512
      int row = p >> 2;
      int kc = (p & 3) ^ ((row >> 1) & 3);
      async_copy16(&Bt[(size_t)(n_base + row) * K + k0 + kc * 8], &Bs[(size_t)p * 8]);
    }
    __syncthreads();
    bf16x8 af[2], bfr[4];
#pragma unroll
    for (int mi = 0; mi < 2; mi++) {
      int r = wm * 32 + mi * 16 + l16;
      int kc = quad ^ ((r >> 1) & 3);
      af[mi] = *(const bf16x8*)&As[(size_t)(r * 4 + kc) * 8];
    }
#pragma unroll
    for (int ni = 0; ni < 4; ni++) {
      int r = wn * 64 + ni * 16 + l16;
      int kc = quad ^ ((r >> 1) & 3);
      bfr[ni] = *(const bf16x8*)&Bs[(size_t)(r * 4 + kc) * 8];
    }
#pragma unroll
    for (int mi = 0; mi < 2; mi++)
#pragma unroll
      for (int ni = 0; ni < 4; ni++)
        acc[mi][ni] = mfma16(af[mi], bfr[ni], acc[mi][ni]);
    __syncthreads();
  }

#pragma unroll
  for (int mi = 0; mi < 2; mi++) {
    int m = m_base + wm * 32 + mi * 16 + quad * 4;
#pragma unroll
    for (int ni = 0; ni < 4; ni++) {
      int n = n_base + wn * 64 + ni * 16 + l16;
      float bv = bias[n];
#pragma unroll
      for (int r2 = 0; r2 < 4; r2++) {
        float v = acc[mi][ni][r2] + bv;
        if (EPI == 2) v = gelu_tanh(v);
        if (EPI == 0) ((float*)outp)[(size_t)(m + r2) * N + n] = v;
        else          ((bf16_t*)outp)[(size_t)(m + r2) * N + n] = (bf16_t)v;
      }
    }
  }
}

// ---------- fused dual-score attention, m97-style block-cooperative structure ----------
// grid (nq/128, H, B), 256 threads = 4 waves. Block: 128 q-rows; wave wv: 32 q-rows
// (2 independent 16-row mt tiles). 16 key-blocks (64 keys) streamed via async
// global_load_lds into shared kc/kv/vt tiles, 2 barriers per key-block.
// No-max softmax: scores O(10), exp2 safe in f32.
__global__ __launch_bounds__(256, 2) void attn_kernel(
    const bf16_t* __restrict__ qc, const bf16_t* __restrict__ qv,
    const bf16_t* __restrict__ kcb, const bf16_t* __restrict__ vkb,
    const bf16_t* __restrict__ vt, const float* __restrict__ lamp,
    bf16_t* __restrict__ vout) {
  const int b = blockIdx.z, h = blockIdx.y;
  const int tid = threadIdx.x;
  const int lane = tid & 63, wv = tid >> 6;
  const int quad = lane >> 4, l16 = lane & 15;
  const int qrow0 = blockIdx.x * 128 + wv * 32;
  const float SCL = 0.125f * 1.4426950408889634f;  // 1/sqrt(64) * log2(e)
  const float C1 = SCL, C2 = lamp[0] * SCL;

  __shared__ __align__(16) bf16_t kcS[64 * 64];
  __shared__ __align__(16) bf16_t kvS[64 * 64];
  __shared__ __align__(16) bf16_t vtS[64 * 64];
  __shared__ __align__(16) bf16_t sP[4][32 * 64];
  bf16_t* sPw = sP[wv];

  // Q fragments: A[m=q (l16)][k=d (ks*32+quad*8+j)]
  bf16x8 qcf[2][2], qvf[2][2];
#pragma unroll
  for (int mt = 0; mt < 2; mt++)
#pragma unroll
    for (int ks = 0; ks < 2; ks++) {
      size_t o = ((size_t)b * 4096 + qrow0 + mt * 16 + l16) * 512 + h * 64 + ks * 32 + quad * 8;
      qcf[mt][ks] = *(const bf16x8*)&qc[o];
      qvf[mt][ks] = *(const bf16x8*)&qv[o];
    }

  f32x4 O[2][4] = {};
  float ls[2][4] = {};

  for (int kb = 0; kb < 16; kb++) {
    // ---- stage kc/kv/vt 64x64 tiles (8 KB each): source-side XOR swizzle ----
#pragma unroll
    for (int i = 0; i < 2; i++) {
      int p = i * 256 + tid;            // 512 chunks of 16B per tile
      int row = p >> 3;                 // key row (kc/kv) or d row (vt)
      int gc = (p & 7) ^ (row & 7);     // global chunk for this LDS slot
      async_copy16(&kcb[((size_t)b * 1024 + kb * 64 + row) * 512 + h * 64 + gc * 8],
                   &kcS[(size_t)p * 8]);
      async_copy16(&vkb[((size_t)b * 1024 + kb * 64 + row) * 1024 + 512 + h * 64 + gc * 8],
                   &kvS[(size_t)p * 8]);
      async_copy16(&vt[((size_t)((b * 8 + h) * 64) + row) * 1024 + kb * 64 + gc * 8],
                   &vtS[(size_t)p * 8]);
    }
    __syncthreads();

    // ---- QK^T + exp -> per-wave P ----
#pragma unroll
    for (int nt = 0; nt < 4; nt++) {
      int krow = nt * 16 + l16;
      int kb8 = krow & 7;
      bf16x8 kc0 = *(const bf16x8*)&kcS[(size_t)(krow * 8 + (quad ^ kb8)) * 8];
      bf16x8 kc1 = *(const bf16x8*)&kcS[(size_t)(krow * 8 + ((4 + quad) ^ kb8)) * 8];
      bf16x8 kv0 = *(const bf16x8*)&kvS[(size_t)(krow * 8 + (quad ^ kb8)) * 8];
      bf16x8 kv1 = *(const bf16x8*)&kvS[(size_t)(krow * 8 + ((4 + quad) ^ kb8)) * 8];
#pragma unroll
      for (int mt = 0; mt < 2; mt++) {
        f32x4 sc = {};
        sc = mfma16(qcf[mt][0], kc0, sc);
        sc = mfma16(qcf[mt][1], kc1, sc);
        f32x4 sv = {};
        sv = mfma16(qvf[mt][0], kv0, sv);
        sv = mfma16(qvf[mt][1], kv1, sv);
#pragma unroll
        for (int r = 0; r < 4; r++) {
          float p = exp2f(sc[r] * C1 + sv[r] * C2);
          ls[mt][r] += p;
          int prow = mt * 16 + quad * 4 + r;
          int col = nt * 16 + l16;
          sPw[prow * 64 + (((col >> 3) ^ (prow & 7)) * 8) + (col & 7)] = (bf16_t)p;
        }
      }
    }
    // RAW: this wave's P writes must land before its reads (per-wave buffer)
    asm volatile("s_waitcnt lgkmcnt(0)" ::: "memory");

    // ---- PV: O[mt] += P[mt] @ V ----
#pragma unroll
    for (int ks2 = 0; ks2 < 2; ks2++) {
      bf16x8 pa[2];
#pragma unroll
      for (int mt = 0; mt < 2; mt++) {
        int prow = mt * 16 + l16;
        pa[mt] = *(const bf16x8*)&sPw[(size_t)(prow * 8 + ((ks2 * 4 + quad) ^ (prow & 7))) * 8];
      }
#pragma unroll
      for (int ntd = 0; ntd < 4; ntd++) {
        int drow = ntd * 16 + l16;
        bf16x8 vb = *(const bf16x8*)&vtS[(size_t)(drow * 8 + ((ks2 * 4 + quad) ^ (drow & 7))) * 8];
        O[0][ntd] = mfma16(pa[0], vb, O[0][ntd]);
        O[1][ntd] = mfma16(pa[1], vb, O[1][ntd]);
      }
    }
    __syncthreads();  // protect kc/kv/vt tiles before next stage (also WAR for sPw)
  }

  // ---- epilogue: denominator + write ----
#pragma unroll
  for (int mt = 0; mt < 2; mt++) {
    float inv[4];
#pragma unroll
    for (int r = 0; r < 4; r++) {
      float v = ls[mt][r];
      v += __shfl_xor(v, 1);
      v += __shfl_xor(v, 2);
      v += __shfl_xor(v, 4);
      v += __shfl_xor(v, 8);
      inv[r] = 1.f / v;
    }
#pragma unroll
    for (int ntd = 0; ntd < 4; ntd++)
#pragma unroll
      for (int r = 0; r < 4; r++) {
        size_t o = ((size_t)b * 4096 + qrow0 + mt * 16 + quad * 4 + r) * 512 + h * 64 + ntd * 16 + l16;
        vout[o] = (bf16_t)(O[mt][ntd][r] * inv[r]);
      }
  }
}

extern "C" void kernel_launch(void* const* d_in, const int* in_sizes, int n_in,
                              void* d_out, int out_size, void* d_ws, size_t ws_size,
                              hipStream_t stream) {
  (void)in_sizes; (void)n_in; (void)out_size; (void)ws_size;
  const float* coords = (const float*)d_in[0];
  const float* values = (const float*)d_in[1];
  const float* Lv     = (const float*)d_in[2];
  const float* Lc     = (const float*)d_in[3];
  const float* lam    = (const float*)d_in[4];
  const float* lvn_g  = (const float*)d_in[5];
  const float* lvn_b  = (const float*)d_in[6];
  const float* lcn_g  = (const float*)d_in[7];
  const float* lcn_b  = (const float*)d_in[8];
  const float* ck_w = (const float*)d_in[9];  const float* ck_b = (const float*)d_in[10]; const float* ck_g = (const float*)d_in[11];
  const float* cq_w = (const float*)d_in[12]; const float* cq_b = (const float*)d_in[13]; const float* cq_g = (const float*)d_in[14];
  const float* vq_w = (const float*)d_in[15]; const float* vq_b = (const float*)d_in[16]; const float* vq_g = (const float*)d_in[17];
  const float* vk_w = (const float*)d_in[18]; const float* vk_b = (const float*)d_in[19];
  const float* op_w = (const float*)d_in[20]; const float* op_b = (const float*)d_in[21];
  const float* oln_g = (const float*)d_in[22]; const float* oln_b = (const float*)d_in[23];
  const float* m1_w = (const float*)d_in[24]; const float* m1_b = (const float*)d_in[25];
  const float* m2_w = (const float*)d_in[26]; const float* m2_b = (const float*)d_in[27];
  const float* m3_w = (const float*)d_in[28]; const float* m3_b = (const float*)d_in[29];

  char* ws = (char*)d_ws;
  size_t off = 0;
  auto alloc = [&](size_t bytes) { void* p = ws + off; off += (bytes + 255) & ~(size_t)255; return p; };

  // persistent region
  bf16_t* wt_m1 = (bf16_t*)alloc((size_t)512 * 2048 * 2);
  bf16_t* wt_m2 = (bf16_t*)alloc((size_t)2048 * 2048 * 2);
  bf16_t* wt_m3 = (bf16_t*)alloc((size_t)2048 * 512 * 2);
  float*  scr0  = (float*) alloc((size_t)16384 * 512 * 4);
  bf16_t* qv_bf = (bf16_t*)alloc((size_t)16384 * 512 * 2);
  bf16_t* qc_bf = (bf16_t*)alloc((size_t)16384 * 512 * 2);
  bf16_t* voutb = (bf16_t*)alloc((size_t)16384 * 512 * 2);
  bf16_t* h0    = (bf16_t*)alloc((size_t)16384 * 512 * 2);
  bf16_t* h1    = (bf16_t*)alloc((size_t)16384 * 2048 * 2);
  bf16_t* h2    = (bf16_t*)alloc((size_t)16384 * 2048 * 2);

  // overlay region: everything here is dead before h1 is written (m1 GEMM)
  size_t ov = (size_t)((char*)h1 - ws);
  auto oalloc = [&](size_t bytes) { void* p = ws + ov; ov += (bytes + 255) & ~(size_t)255; return p; };
  bf16_t* wt_vk = (bf16_t*)oalloc((size_t)1024 * 512 * 2);
  bf16_t* wt_ck = (bf16_t*)oalloc((size_t)512 * 128 * 2);
  bf16_t* wt_cq = (bf16_t*)oalloc((size_t)512 * 128 * 2);
  bf16_t* wt_vq = (bf16_t*)oalloc((size_t)512 * 512 * 2);
  bf16_t* wt_op = (bf16_t*)oalloc((size_t)512 * 512 * 2);
  bf16_t* lv_ln = (bf16_t*)oalloc((size_t)4096 * 512 * 2);
  bf16_t* lc_ln = (bf16_t*)oalloc((size_t)4096 * 128 * 2);
  bf16_t* vkob  = (bf16_t*)oalloc((size_t)4096 * 1024 * 2);
  float*  kc_f  = (float*) oalloc((size_t)4096 * 512 * 4);
  bf16_t* kc_bf = (bf16_t*)oalloc((size_t)4096 * 512 * 2);
  bf16_t* val_bf= (bf16_t*)oalloc((size_t)16384 * 512 * 2);
  bf16_t* crd_bf= (bf16_t*)oalloc((size_t)16384 * 128 * 2);
  bf16_t* vt    = (bf16_t*)oalloc((size_t)4 * 512 * 1024 * 2);

  // ---- single batched transpose launch for all 8 weights ----
  TransBatch tb8;
  const float* srcs[8] = {vk_w, ck_w, cq_w, vq_w, op_w, m1_w, m2_w, m3_w};
  bf16_t* dsts[8] = {wt_vk, wt_ck, wt_cq, wt_vq, wt_op, wt_m1, wt_m2, wt_m3};
  int Ks[8] = {512, 128, 128, 512, 512, 512, 2048, 2048};
  int Ns[8] = {1024, 512, 512, 512, 512, 2048, 2048, 512};
  int cum = 0;
  for (int i = 0; i < 8; i++) {
    tb8.src[i] = srcs[i]; tb8.dst[i] = dsts[i];
    tb8.K[i] = Ks[i]; tb8.N[i] = Ns[i];
    tb8.bx[i] = Ns[i] / 32;
    tb8.base[i] = cum;
    cum += (Ns[i] / 32) * (Ks[i] / 32);
  }
  transpose_batch_kernel<<<cum, dim3(32, 8), 0, stream>>>(tb8);

  cvt2_bf16_kernel<<<(16384 * 512 / 4 + 16384 * 128 / 4 + 255) / 256, 256, 0, stream>>>(
      values, val_bf, 16384 * 512 / 4, coords, crd_bf, 16384 * 128 / 4);

  ln_kernel<512><<<4096, 512, 0, stream>>>(Lv, lvn_g, lvn_b, lv_ln);
  ln_kernel<128><<<4096, 128, 0, stream>>>(Lc, lcn_g, lcn_b, lc_ln);

  gemm64<1><<<dim3(8, 64), 256, 0, stream>>>(lv_ln, wt_vk, vk_b, vkob, 4096, 1024, 512);
  gemm64<0><<<dim3(4, 64), 256, 0, stream>>>(lc_ln, wt_ck, ck_b, kc_f, 4096, 512, 128);
  rms_kernel<<<4096, 512, 0, stream>>>(kc_f, ck_g, kc_bf);

  gemm64<0><<<dim3(4, 256), 256, 0, stream>>>(val_bf, wt_vq, vq_b, scr0, 16384, 512, 512);
  rms_kernel<<<16384, 512, 0, stream>>>(scr0, vq_g, qv_bf);
  gemm64<0><<<dim3(4, 256), 256, 0, stream>>>(crd_bf, wt_cq, cq_b, scr0, 16384, 512, 128);
  rms_kernel<<<16384, 512, 0, stream>>>(scr0, cq_g, qc_bf);

  transpose_v_kernel<<<dim3(16, 32, 4), dim3(32, 8), 0, stream>>>(vkob, vt);

  attn_kernel<<<dim3(32, 8, 4), 256, 0, stream>>>(qc_bf, qv_bf, kc_bf, vkob, vt, lam, voutb);

  gemm64<0><<<dim3(4, 256), 256, 0, stream>>>(voutb, wt_op, op_b, scr0, 16384, 512, 512);
  ln_kernel<512><<<16384, 512, 0, stream>>>(scr0, oln_g, oln_b, h0);

  gemm_bt<2><<<dim3(16, 128), 256, 0, stream>>>(h0, wt_m1, m1_b, h1, 16384, 2048, 512);
  gemm_bt<2><<<dim3(16, 128), 256, 0, stream>>>(h1, wt_m2, m2_b, h2, 16384, 2048, 2048);
  gemm64<0><<<dim3(4, 256), 256, 0, stream>>>(h2, wt_m3, m3_b, (float*)d_out, 16384, 512, 2048);
}

// Round 7
// 673.757 us; speedup vs baseline: 1.0783x; 1.0399x over previous
//
#include <hip/hip_runtime.h>
#include <cstdint>
#include <cstddef>

typedef __bf16 bf16_t;
typedef __bf16 bf16x8 __attribute__((ext_vector_type(8)));
typedef __bf16 bf16x4 __attribute__((ext_vector_type(4)));
typedef float  f32x4  __attribute__((ext_vector_type(4)));

typedef __attribute__((address_space(1))) void gvoid_t;
typedef __attribute__((address_space(3))) void lvoid_t;

__device__ __forceinline__ f32x4 mfma16(bf16x8 a, bf16x8 b, f32x4 c) {
  return __builtin_amdgcn_mfma_f32_16x16x32_bf16(a, b, c, 0, 0, 0);
}

__device__ __forceinline__ void async_copy16(const void* g, void* l) {
  __builtin_amdgcn_global_load_lds((gvoid_t*)g, (lvoid_t*)l, 16, 0, 0);
}

__device__ __forceinline__ float gelu_tanh(float x) {
  // jax.nn.gelu approximate=True
  float u = 0.7978845608028654f * (x + 0.044715f * x * x * x);
  float e = exp2f(2.8853900817779268f * u);   // e^{2u}
  float t = 1.f - 2.f / (e + 1.f);            // tanh(u)
  return 0.5f * x * (1.f + t);
}

// ---------- batched weight transpose: f32 [K,N] -> bf16 [N,K], 8 matrices, 1 launch ----------
struct TransBatch {
  const float* src[8];
  bf16_t* dst[8];
  int K[8], N[8], bx[8], base[8];  // base = starting linear tile id
};

__global__ void transpose_batch_kernel(TransBatch d) {
  int id = blockIdx.x;
  int mi = 0;
#pragma unroll
  for (int j = 1; j < 8; j++)
    if (id >= d.base[j]) mi = j;
  int local = id - d.base[mi];
  int bxw = d.bx[mi];
  int n0 = (local % bxw) * 32, k0 = (local / bxw) * 32;
  const float* in = d.src[mi];
  bf16_t* out = d.dst[mi];
  int K = d.K[mi], N = d.N[mi];

  __shared__ float t[32][33];
  int tx = threadIdx.x, ty = threadIdx.y;
#pragma unroll
  for (int i = 0; i < 4; i++)
    t[ty + i * 8][tx] = in[(size_t)(k0 + ty + i * 8) * N + n0 + tx];
  __syncthreads();
#pragma unroll
  for (int i = 0; i < 4; i++)
    out[(size_t)(n0 + ty + i * 8) * K + k0 + tx] = (bf16_t)t[tx][ty + i * 8];
}

// ---------- V transpose: vk bf16 [4][1024][1024] (cols 0..511) -> vt [4][512][1024] ----------
__global__ void transpose_v_kernel(const bf16_t* __restrict__ vk, bf16_t* __restrict__ vt) {
  __shared__ bf16_t t[32][33];
  int b = blockIdx.z;
  int d0 = blockIdx.x * 32, m0 = blockIdx.y * 32;
  int tx = threadIdx.x, ty = threadIdx.y;
#pragma unroll
  for (int i = 0; i < 4; i++)
    t[ty + i * 8][tx] = vk[((size_t)b * 1024 + m0 + ty + i * 8) * 1024 + d0 + tx];
  __syncthreads();
#pragma unroll
  for (int i = 0; i < 4; i++)
    vt[((size_t)b * 512 + d0 + ty + i * 8) * 1024 + m0 + tx] = t[tx][ty + i * 8];
}

// ---------- f32 -> bf16 convert, two tensors in one launch ----------
__global__ void cvt2_bf16_kernel(const float* __restrict__ a, bf16_t* __restrict__ oa, int n4a,
                                 const float* __restrict__ b, bf16_t* __restrict__ ob, int n4b) {
  int i = blockIdx.x * blockDim.x + threadIdx.x;
  const float* s;
  bf16_t* o;
  int j;
  if (i < n4a) { s = a; o = oa; j = i; }
  else { j = i - n4a; if (j >= n4b) return; s = b; o = ob; }
  float4 v = ((const float4*)s)[j];
  bf16x4 r = {(bf16_t)v.x, (bf16_t)v.y, (bf16_t)v.z, (bf16_t)v.w};
  ((bf16x4*)o)[j] = r;
}

// ---------- LayerNorm (one row per block, blockDim = D), templated input type ----------
template <int D, typename TI>
__global__ void ln_kernel(const TI* __restrict__ x, const float* __restrict__ g,
                          const float* __restrict__ bb, bf16_t* __restrict__ out) {
  int row = blockIdx.x, t = threadIdx.x;
  float v = (float)x[(size_t)row * D + t];
  float s = v, s2 = v * v;
#pragma unroll
  for (int o = 32; o > 0; o >>= 1) { s += __shfl_xor(s, o); s2 += __shfl_xor(s2, o); }
  __shared__ float rs[8], rs2[8];
  constexpr int NW = D / 64;
  int w = t >> 6;
  if ((t & 63) == 0) { rs[w] = s; rs2[w] = s2; }
  __syncthreads();
  if (t < 64) {
    float a = (t < NW) ? rs[t] : 0.f;
    float a2 = (t < NW) ? rs2[t] : 0.f;
#pragma unroll
    for (int o = 4; o > 0; o >>= 1) { a += __shfl_xor(a, o); a2 += __shfl_xor(a2, o); }
    if (t == 0) { rs[0] = a; rs2[0] = a2; }
  }
  __syncthreads();
  float mu = rs[0] * (1.f / D);
  float var = rs2[0] * (1.f / D) - mu * mu;
  float rr = rsqrtf(var + 1e-5f);
  out[(size_t)row * D + t] = (bf16_t)((v - mu) * rr * g[t] + bb[t]);
}

// ---------- RMSNorm over 512 (one row per block, blockDim = 512), templated input ----------
template <typename TI>
__global__ void rms_kernel(const TI* __restrict__ x, const float* __restrict__ g,
                           bf16_t* __restrict__ out) {
  int row = blockIdx.x, t = threadIdx.x;
  float v = (float)x[(size_t)row * 512 + t];
  float s2 = v * v;
#pragma unroll
  for (int o = 32; o > 0; o >>= 1) s2 += __shfl_xor(s2, o);
  __shared__ float rs2[8];
  int w = t >> 6;
  if ((t & 63) == 0) rs2[w] = s2;
  __syncthreads();
  if (t < 64) {
    float a = (t < 8) ? rs2[t] : 0.f;
#pragma unroll
    for (int o = 4; o > 0; o >>= 1) a += __shfl_xor(a, o);
    if (t == 0) rs2[0] = a;
  }
  __syncthreads();
  float r = rsqrtf(rs2[0] * (1.f / 512.f) + 1e-6f);
  out[(size_t)row * 512 + t] = (bf16_t)(v * r * g[t]);
}

// ---------- GEMM 128x128 tile, BK=64, 16x16x32 MFMA, 32 MFMA per barrier-pair ----------
// EPI: 0 = f32 out (+bias), 1 = bf16 out (+bias), 2 = bf16 out (+bias, gelu)
// LDS 32 KB total -> still 2 blocks/CU. 8-chunk XOR swizzle c^(row&7): reads <=2-way.
template <int EPI>
__global__ __launch_bounds__(256, 2) void gemm_bt(
    const bf16_t* __restrict__ A, const bf16_t* __restrict__ Bt,
    const float* __restrict__ bias, void* __restrict__ outp,
    int M, int N, int K) {
  __shared__ __align__(16) bf16_t As[128 * 64];
  __shared__ __align__(16) bf16_t Bs[128 * 64];
  const int tid = threadIdx.x;
  const int lane = tid & 63, wv = tid >> 6;
  const int quad = lane >> 4, l16 = lane & 15;
  const int m_base = blockIdx.y * 128, n_base = blockIdx.x * 128;
  const int wm = wv & 1, wn = wv >> 1;
  f32x4 acc[4][4] = {};

  for (int k0 = 0; k0 < K; k0 += 64) {
#pragma unroll
    for (int c = 0; c < 4; c++) {
      int p = c * 256 + tid;                 // 1024 chunks: 128 rows x 8 chunks of 8 bf16
      int row = p >> 3;
      int gc = (p & 7) ^ (row & 7);          // XOR swizzle
      async_copy16(&A[(size_t)(m_base + row) * K + k0 + gc * 8], &As[(size_t)p * 8]);
      async_copy16(&Bt[(size_t)(n_base + row) * K + k0 + gc * 8], &Bs[(size_t)p * 8]);
    }
    __syncthreads();
#pragma unroll
    for (int ks = 0; ks < 2; ks++) {
      bf16x8 af[4], bfr[4];
#pragma unroll
      for (int mi = 0; mi < 4; mi++) {
        int r = wm * 64 + mi * 16 + l16;
        int c = (ks * 4 + quad) ^ (r & 7);
        af[mi] = *(const bf16x8*)&As[(size_t)(r * 8 + c) * 8];
      }
#pragma unroll
      for (int ni = 0; ni < 4; ni++) {
        int r = wn * 64 + ni * 16 + l16;
        int c = (ks * 4 + quad) ^ (r & 7);
        bfr[ni] = *(const bf16x8*)&Bs[(size_t)(r * 8 + c) * 8];
      }
#pragma unroll
      for (int mi = 0; mi < 4; mi++)
#pragma unroll
        for (int ni = 0; ni < 4; ni++)
          acc[mi][ni] = mfma16(af[mi], bfr[ni], acc[mi][ni]);
    }
    __syncthreads();
  }

#pragma unroll
  for (int mi = 0; mi < 4; mi++) {
    int m = m_base + wm * 64 + mi * 16 + quad * 4;
#pragma unroll
    for (int ni = 0; ni < 4; ni++) {
      int n = n_base + wn * 64 + ni * 16 + l16;
      float bv = bias[n];
#pragma unroll
      for (int r2 = 0; r2 < 4; r2++) {
        float v = acc[mi][ni][r2] + bv;
        if (EPI == 2) v = gelu_tanh(v);
        if (EPI == 0) ((float*)outp)[(size_t)(m + r2) * N + n] = v;
        else          ((bf16_t*)outp)[(size_t)(m + r2) * N + n] = (bf16_t)v;
      }
    }
  }
}

// ---------- GEMM 64x128 tile for small-K tail GEMMs (2x the blocks of 128x128) ----------
// 4 waves, each 32x64 (2 mt x 4 ni of 16x16). 12 KB LDS. BK=32.
template <int EPI>
__global__ __launch_bounds__(256, 2) void gemm64(
    const bf16_t* __restrict__ A, const bf16_t* __restrict__ Bt,
    const float* __restrict__ bias, void* __restrict__ outp,
    int M, int N, int K) {
  __shared__ __align__(16) bf16_t As[64 * 32];
  __shared__ __align__(16) bf16_t Bs[128 * 32];
  const int tid = threadIdx.x;
  const int lane = tid & 63, wv = tid >> 6;
  const int quad = lane >> 4, l16 = lane & 15;
  const int m_base = blockIdx.y * 64, n_base = blockIdx.x * 128;
  const int wm = wv & 1, wn = wv >> 1;
  f32x4 acc[2][4] = {};

  for (int k0 = 0; k0 < K; k0 += 32) {
    {
      int p = tid;                           // A: 64 rows x 4 chunks = 256
      int row = p >> 2;
      int kc = (p & 3) ^ ((row >> 1) & 3);
      async_copy16(&A[(size_t)(m_base + row) * K + k0 + kc * 8], &As[(size_t)p * 8]);
    }
#pragma unroll
    for (int c = 0; c < 2; c++) {
      int p = c * 256 + tid;                 // B: 128 rows x 4 chunks = 512
      int row = p >> 2;
      int kc = (p & 3) ^ ((row >> 1) & 3);
      async_copy16(&Bt[(size_t)(n_base + row) * K + k0 + kc * 8], &Bs[(size_t)p * 8]);
    }
    __syncthreads();
    bf16x8 af[2], bfr[4];
#pragma unroll
    for (int mi = 0; mi < 2; mi++) {
      int r = wm * 32 + mi * 16 + l16;
      int kc = quad ^ ((r >> 1) & 3);
      af[mi] = *(const bf16x8*)&As[(size_t)(r * 4 + kc) * 8];
    }
#pragma unroll
    for (int ni = 0; ni < 4; ni++) {
      int r = wn * 64 + ni * 16 + l16;
      int kc = quad ^ ((r >> 1) & 3);
      bfr[ni] = *(const bf16x8*)&Bs[(size_t)(r * 4 + kc) * 8];
    }
#pragma unroll
    for (int mi = 0; mi < 2; mi++)
#pragma unroll
      for (int ni = 0; ni < 4; ni++)
        acc[mi][ni] = mfma16(af[mi], bfr[ni], acc[mi][ni]);
    __syncthreads();
  }

#pragma unroll
  for (int mi = 0; mi < 2; mi++) {
    int m = m_base + wm * 32 + mi * 16 + quad * 4;
#pragma unroll
    for (int ni = 0; ni < 4; ni++) {
      int n = n_base + wn * 64 + ni * 16 + l16;
      float bv = bias[n];
#pragma unroll
      for (int r2 = 0; r2 < 4; r2++) {
        float v = acc[mi][ni][r2] + bv;
        if (EPI == 2) v = gelu_tanh(v);
        if (EPI == 0) ((float*)outp)[(size_t)(m + r2) * N + n] = v;
        else          ((bf16_t*)outp)[(size_t)(m + r2) * N + n] = (bf16_t)v;
      }
    }
  }
}

// ---------- fused dual-score attention, m97-style block-cooperative structure ----------
__global__ __launch_bounds__(256, 2) void attn_kernel(
    const bf16_t* __restrict__ qc, const bf16_t* __restrict__ qv,
    const bf16_t* __restrict__ kcb, const bf16_t* __restrict__ vkb,
    const bf16_t* __restrict__ vt, const float* __restrict__ lamp,
    bf16_t* __restrict__ vout) {
  const int b = blockIdx.z, h = blockIdx.y;
  const int tid = threadIdx.x;
  const int lane = tid & 63, wv = tid >> 6;
  const int quad = lane >> 4, l16 = lane & 15;
  const int qrow0 = blockIdx.x * 128 + wv * 32;
  const float SCL = 0.125f * 1.4426950408889634f;  // 1/sqrt(64) * log2(e)
  const float C1 = SCL, C2 = lamp[0] * SCL;

  __shared__ __align__(16) bf16_t kcS[64 * 64];
  __shared__ __align__(16) bf16_t kvS[64 * 64];
  __shared__ __align__(16) bf16_t vtS[64 * 64];
  __shared__ __align__(16) bf16_t sP[4][32 * 64];
  bf16_t* sPw = sP[wv];

  // Q fragments: A[m=q (l16)][k=d (ks*32+quad*8+j)]
  bf16x8 qcf[2][2], qvf[2][2];
#pragma unroll
  for (int mt = 0; mt < 2; mt++)
#pragma unroll
    for (int ks = 0; ks < 2; ks++) {
      size_t o = ((size_t)b * 4096 + qrow0 + mt * 16 + l16) * 512 + h * 64 + ks * 32 + quad * 8;
      qcf[mt][ks] = *(const bf16x8*)&qc[o];
      qvf[mt][ks] = *(const bf16x8*)&qv[o];
    }

  f32x4 O[2][4] = {};
  float ls[2][4] = {};

  for (int kb = 0; kb < 16; kb++) {
    // ---- stage kc/kv/vt 64x64 tiles (8 KB each): source-side XOR swizzle ----
#pragma unroll
    for (int i = 0; i < 2; i++) {
      int p = i * 256 + tid;            // 512 chunks of 16B per tile
      int row = p >> 3;                 // key row (kc/kv) or d row (vt)
      int gc = (p & 7) ^ (row & 7);     // global chunk for this LDS slot
      async_copy16(&kcb[((size_t)b * 1024 + kb * 64 + row) * 512 + h * 64 + gc * 8],
                   &kcS[(size_t)p * 8]);
      async_copy16(&vkb[((size_t)b * 1024 + kb * 64 + row) * 1024 + 512 + h * 64 + gc * 8],
                   &kvS[(size_t)p * 8]);
      async_copy16(&vt[((size_t)((b * 8 + h) * 64) + row) * 1024 + kb * 64 + gc * 8],
                   &vtS[(size_t)p * 8]);
    }
    __syncthreads();

    // ---- QK^T + exp -> per-wave P ----
#pragma unroll
    for (int nt = 0; nt < 4; nt++) {
      int krow = nt * 16 + l16;
      int kb8 = krow & 7;
      bf16x8 kc0 = *(const bf16x8*)&kcS[(size_t)(krow * 8 + (quad ^ kb8)) * 8];
      bf16x8 kc1 = *(const bf16x8*)&kcS[(size_t)(krow * 8 + ((4 + quad) ^ kb8)) * 8];
      bf16x8 kv0 = *(const bf16x8*)&kvS[(size_t)(krow * 8 + (quad ^ kb8)) * 8];
      bf16x8 kv1 = *(const bf16x8*)&kvS[(size_t)(krow * 8 + ((4 + quad) ^ kb8)) * 8];
#pragma unroll
      for (int mt = 0; mt < 2; mt++) {
        f32x4 sc = {};
        sc = mfma16(qcf[mt][0], kc0, sc);
        sc = mfma16(qcf[mt][1], kc1, sc);
        f32x4 sv = {};
        sv = mfma16(qvf[mt][0], kv0, sv);
        sv = mfma16(qvf[mt][1], kv1, sv);
#pragma unroll
        for (int r = 0; r < 4; r++) {
          float p = exp2f(sc[r] * C1 + sv[r] * C2);
          ls[mt][r] += p;
          int prow = mt * 16 + quad * 4 + r;
          int col = nt * 16 + l16;
          sPw[prow * 64 + (((col >> 3) ^ (prow & 7)) * 8) + (col & 7)] = (bf16_t)p;
        }
      }
    }
    // RAW: this wave's P writes must land before its reads (per-wave buffer)
    asm volatile("s_waitcnt lgkmcnt(0)" ::: "memory");

    // ---- PV: O[mt] += P[mt] @ V ----
#pragma unroll
    for (int ks2 = 0; ks2 < 2; ks2++) {
      bf16x8 pa[2];
#pragma unroll
      for (int mt = 0; mt < 2; mt++) {
        int prow = mt * 16 + l16;
        pa[mt] = *(const bf16x8*)&sPw[(size_t)(prow * 8 + ((ks2 * 4 + quad) ^ (prow & 7))) * 8];
      }
#pragma unroll
      for (int ntd = 0; ntd < 4; ntd++) {
        int drow = ntd * 16 + l16;
        bf16x8 vb = *(const bf16x8*)&vtS[(size_t)(drow * 8 + ((ks2 * 4 + quad) ^ (drow & 7))) * 8];
        O[0][ntd] = mfma16(pa[0], vb, O[0][ntd]);
        O[1][ntd] = mfma16(pa[1], vb, O[1][ntd]);
      }
    }
    __syncthreads();  // protect kc/kv/vt tiles before next stage (also WAR for sPw)
  }

  // ---- epilogue: denominator + write ----
#pragma unroll
  for (int mt = 0; mt < 2; mt++) {
    float inv[4];
#pragma unroll
    for (int r = 0; r < 4; r++) {
      float v = ls[mt][r];
      v += __shfl_xor(v, 1);
      v += __shfl_xor(v, 2);
      v += __shfl_xor(v, 4);
      v += __shfl_xor(v, 8);
      inv[r] = 1.f / v;
    }
#pragma unroll
    for (int ntd = 0; ntd < 4; ntd++)
#pragma unroll
      for (int r = 0; r < 4; r++) {
        size_t o = ((size_t)b * 4096 + qrow0 + mt * 16 + quad * 4 + r) * 512 + h * 64 + ntd * 16 + l16;
        vout[o] = (bf16_t)(O[mt][ntd][r] * inv[r]);
      }
  }
}

extern "C" void kernel_launch(void* const* d_in, const int* in_sizes, int n_in,
                              void* d_out, int out_size, void* d_ws, size_t ws_size,
                              hipStream_t stream) {
  (void)in_sizes; (void)n_in; (void)out_size; (void)ws_size;
  const float* coords = (const float*)d_in[0];
  const float* values = (const float*)d_in[1];
  const float* Lv     = (const float*)d_in[2];
  const float* Lc     = (const float*)d_in[3];
  const float* lam    = (const float*)d_in[4];
  const float* lvn_g  = (const float*)d_in[5];
  const float* lvn_b  = (const float*)d_in[6];
  const float* lcn_g  = (const float*)d_in[7];
  const float* lcn_b  = (const float*)d_in[8];
  const float* ck_w = (const float*)d_in[9];  const float* ck_b = (const float*)d_in[10]; const float* ck_g = (const float*)d_in[11];
  const float* cq_w = (const float*)d_in[12]; const float* cq_b = (const float*)d_in[13]; const float* cq_g = (const float*)d_in[14];
  const float* vq_w = (const float*)d_in[15]; const float* vq_b = (const float*)d_in[16]; const float* vq_g = (const float*)d_in[17];
  const float* vk_w = (const float*)d_in[18]; const float* vk_b = (const float*)d_in[19];
  const float* op_w = (const float*)d_in[20]; const float* op_b = (const float*)d_in[21];
  const float* oln_g = (const float*)d_in[22]; const float* oln_b = (const float*)d_in[23];
  const float* m1_w = (const float*)d_in[24]; const float* m1_b = (const float*)d_in[25];
  const float* m2_w = (const float*)d_in[26]; const float* m2_b = (const float*)d_in[27];
  const float* m3_w = (const float*)d_in[28]; const float* m3_b = (const float*)d_in[29];

  char* ws = (char*)d_ws;
  size_t off = 0;
  auto alloc = [&](size_t bytes) { void* p = ws + off; off += (bytes + 255) & ~(size_t)255; return p; };

  // persistent region
  bf16_t* wt_m1 = (bf16_t*)alloc((size_t)512 * 2048 * 2);
  bf16_t* wt_m2 = (bf16_t*)alloc((size_t)2048 * 2048 * 2);
  bf16_t* wt_m3 = (bf16_t*)alloc((size_t)2048 * 512 * 2);
  bf16_t* scr0  = (bf16_t*)alloc((size_t)16384 * 512 * 4);   // bf16 used, f32-sized slot kept
  bf16_t* qv_bf = (bf16_t*)alloc((size_t)16384 * 512 * 2);
  bf16_t* qc_bf = (bf16_t*)alloc((size_t)16384 * 512 * 2);
  bf16_t* voutb = (bf16_t*)alloc((size_t)16384 * 512 * 2);
  bf16_t* h0    = (bf16_t*)alloc((size_t)16384 * 512 * 2);
  bf16_t* h1    = (bf16_t*)alloc((size_t)16384 * 2048 * 2);
  bf16_t* h2    = (bf16_t*)alloc((size_t)16384 * 2048 * 2);

  // overlay region: everything here is dead before h1 is written (m1 GEMM)
  size_t ov = (size_t)((char*)h1 - ws);
  auto oalloc = [&](size_t bytes) { void* p = ws + ov; ov += (bytes + 255) & ~(size_t)255; return p; };
  bf16_t* wt_vk = (bf16_t*)oalloc((size_t)1024 * 512 * 2);
  bf16_t* wt_ck = (bf16_t*)oalloc((size_t)512 * 128 * 2);
  bf16_t* wt_cq = (bf16_t*)oalloc((size_t)512 * 128 * 2);
  bf16_t* wt_vq = (bf16_t*)oalloc((size_t)512 * 512 * 2);
  bf16_t* wt_op = (bf16_t*)oalloc((size_t)512 * 512 * 2);
  bf16_t* lv_ln = (bf16_t*)oalloc((size_t)4096 * 512 * 2);
  bf16_t* lc_ln = (bf16_t*)oalloc((size_t)4096 * 128 * 2);
  bf16_t* vkob  = (bf16_t*)oalloc((size_t)4096 * 1024 * 2);
  bf16_t* kc_b  = (bf16_t*)oalloc((size_t)4096 * 512 * 2);
  bf16_t* kc_bf = (bf16_t*)oalloc((size_t)4096 * 512 * 2);
  bf16_t* val_bf= (bf16_t*)oalloc((size_t)16384 * 512 * 2);
  bf16_t* crd_bf= (bf16_t*)oalloc((size_t)16384 * 128 * 2);
  bf16_t* vt    = (bf16_t*)oalloc((size_t)4 * 512 * 1024 * 2);

  // ---- single batched transpose launch for all 8 weights ----
  TransBatch tb8;
  const float* srcs[8] = {vk_w, ck_w, cq_w, vq_w, op_w, m1_w, m2_w, m3_w};
  bf16_t* dsts[8] = {wt_vk, wt_ck, wt_cq, wt_vq, wt_op, wt_m1, wt_m2, wt_m3};
  int Ks[8] = {512, 128, 128, 512, 512, 512, 2048, 2048};
  int Ns[8] = {1024, 512, 512, 512, 512, 2048, 2048, 512};
  int cum = 0;
  for (int i = 0; i < 8; i++) {
    tb8.src[i] = srcs[i]; tb8.dst[i] = dsts[i];
    tb8.K[i] = Ks[i]; tb8.N[i] = Ns[i];
    tb8.bx[i] = Ns[i] / 32;
    tb8.base[i] = cum;
    cum += (Ns[i] / 32) * (Ks[i] / 32);
  }
  transpose_batch_kernel<<<cum, dim3(32, 8), 0, stream>>>(tb8);

  cvt2_bf16_kernel<<<(16384 * 512 / 4 + 16384 * 128 / 4 + 255) / 256, 256, 0, stream>>>(
      values, val_bf, 16384 * 512 / 4, coords, crd_bf, 16384 * 128 / 4);

  ln_kernel<512, float><<<4096, 512, 0, stream>>>(Lv, lvn_g, lvn_b, lv_ln);
  ln_kernel<128, float><<<4096, 128, 0, stream>>>(Lc, lcn_g, lcn_b, lc_ln);

  gemm64<1><<<dim3(8, 64), 256, 0, stream>>>(lv_ln, wt_vk, vk_b, vkob, 4096, 1024, 512);
  gemm64<1><<<dim3(4, 64), 256, 0, stream>>>(lc_ln, wt_ck, ck_b, kc_b, 4096, 512, 128);
  rms_kernel<bf16_t><<<4096, 512, 0, stream>>>(kc_b, ck_g, kc_bf);

  gemm64<1><<<dim3(4, 256), 256, 0, stream>>>(val_bf, wt_vq, vq_b, scr0, 16384, 512, 512);
  rms_kernel<bf16_t><<<16384, 512, 0, stream>>>(scr0, vq_g, qv_bf);
  gemm64<1><<<dim3(4, 256), 256, 0, stream>>>(crd_bf, wt_cq, cq_b, scr0, 16384, 512, 128);
  rms_kernel<bf16_t><<<16384, 512, 0, stream>>>(scr0, cq_g, qc_bf);

  transpose_v_kernel<<<dim3(16, 32, 4), dim3(32, 8), 0, stream>>>(vkob, vt);

  attn_kernel<<<dim3(32, 8, 4), 256, 0, stream>>>(qc_bf, qv_bf, kc_bf, vkob, vt, lam, voutb);

  gemm64<1><<<dim3(4, 256), 256, 0, stream>>>(voutb, wt_op, op_b, scr0, 16384, 512, 512);
  ln_kernel<512, bf16_t><<<16384, 512, 0, stream>>>(scr0, oln_g, oln_b, h0);

  gemm_bt<2><<<dim3(16, 128), 256, 0, stream>>>(h0, wt_m1, m1_b, h1, 16384, 2048, 512);
  gemm_bt<2><<<dim3(16, 128), 256, 0, stream>>>(h1, wt_m2, m2_b, h2, 16384, 2048, 2048);
  gemm_bt<0><<<dim3(4, 128), 256, 0, stream>>>(h2, wt_m3, m3_b, (float*)d_out, 16384, 512, 2048);
}